// Round 7
// baseline (301.798 us; speedup 1.0000x reference)
//
#include <hip/hip_runtime.h>
#include <hip/hip_bf16.h>
#include <math.h>

#define N_NODES 50000
#define E_EDGES 800000
#define E_TOT   850000   // + self loops
#define NEG_SLOPE 0.2f
#define SCAN_BLOCKS 49   // ceil(50001/1024)

// ---------------------------------------------------------------------------
// Fused: zero offs histogram + int64/int32 edge-index detection
// (values < 50000 -> int64 high words all zero)
// ---------------------------------------------------------------------------
__global__ __launch_bounds__(256) void k_detect0(const unsigned int* __restrict__ ei,
                                                 int* __restrict__ flag,
                                                 int* __restrict__ offs) {
    int gid = blockIdx.x * 256 + threadIdx.x;
    for (int i = gid; i <= N_NODES; i += gridDim.x * 256) offs[i] = 0;
    if (blockIdx.x == 0) {
        __shared__ int anynz;
        if (threadIdx.x == 0) anynz = 0;
        __syncthreads();
        int nz = 0;
        for (int i = threadIdx.x; i < 2048; i += 256)
            nz |= (ei[2 * i + 1] != 0u);
        if (nz) atomicOr(&anynz, 1);
        __syncthreads();
        if (threadIdx.x == 0) *flag = (anynz == 0) ? 1 : 0;
    }
}

__device__ __forceinline__ void edge_nodes(const void* ei, int is64, int e, int& s, int& d) {
    if (e >= E_EDGES) { s = d = e - E_EDGES; return; }   // self loop
    if (is64) {
        const long long* p = (const long long*)ei;
        s = (int)p[e]; d = (int)p[E_EDGES + e];
    } else {
        const int* p = (const int*)ei;
        s = p[e]; d = p[E_EDGES + e];
    }
}

// ---------------------------------------------------------------------------
// CSR build: histogram -> parallel scan -> fill (+16 zero-pad entries)
// ---------------------------------------------------------------------------
__global__ void k_count(const void* __restrict__ ei, const int* __restrict__ flag,
                        int* __restrict__ counts) {
    int e = blockIdx.x * 256 + threadIdx.x;
    if (e >= E_TOT) return;
    int s, d;
    edge_nodes(ei, *flag, e, s, d);
    atomicAdd(&counts[d], 1);
}

// block-local exclusive scan (in place) + per-block total
__global__ __launch_bounds__(1024) void k_scanA(int* __restrict__ offs,
                                                int* __restrict__ partials) {
    __shared__ int lds[1024];
    const int t   = threadIdx.x;
    const int idx = blockIdx.x * 1024 + t;
    int v = (idx <= N_NODES) ? offs[idx] : 0;
    lds[t] = v;
    __syncthreads();
    for (int off = 1; off < 1024; off <<= 1) {
        int u = (t >= off) ? lds[t - off] : 0;
        __syncthreads();
        lds[t] += u;
        __syncthreads();
    }
    int incl = lds[t];
    if (idx <= N_NODES) offs[idx] = incl - v;         // exclusive within chunk
    if (t == 1023) partials[blockIdx.x] = incl;       // chunk total
}

// add scanned partials prefix; emit final offs + cursor copy
__global__ __launch_bounds__(1024) void k_scanC(int* __restrict__ offs,
                                                const int* __restrict__ partials,
                                                int* __restrict__ cursor) {
    __shared__ int sprefix;
    const int t   = threadIdx.x;
    const int bid = blockIdx.x;
    if (t < 64) {
        int p = (t < bid) ? partials[t] : 0;          // bid <= 48 < 64
#pragma unroll
        for (int off = 32; off; off >>= 1) p += __shfl_down(p, off);
        if (t == 0) sprefix = p;
    }
    __syncthreads();
    const int idx = bid * 1024 + t;
    if (idx <= N_NODES) {
        int v = offs[idx] + sprefix;
        offs[idx] = v;
        if (idx < N_NODES) cursor[idx] = v;
    }
}

__global__ void k_fill(const void* __restrict__ ei, const int* __restrict__ flag,
                       int* __restrict__ cursor, int* __restrict__ csr_src) {
    int e = blockIdx.x * 256 + threadIdx.x;
    if (e < 16) csr_src[E_TOT + e] = 0;               // pad (valid node id 0)
    if (e >= E_TOT) return;
    int s, d;
    edge_nodes(ei, *flag, e, s, d);
    int pos = atomicAdd(&cursor[d], 1);
    csr_src[pos] = s;
}

// ---------------------------------------------------------------------------
// K1: h1 = x @ W1 (50000x128 @ 128x64) + per-node attention halves
// ---------------------------------------------------------------------------
__global__ __launch_bounds__(256) void k1_transform(
        const float* __restrict__ x, const float* __restrict__ W1,
        const float* __restrict__ a1s, const float* __restrict__ a1d,
        float* __restrict__ h1, float* __restrict__ as1, float* __restrict__ ad1) {
    __shared__ float ws[128 * 64];
    __shared__ float xs[64 * 132];
    const int t  = threadIdx.x;
    const int nb = blockIdx.x * 64;
    for (int i = t * 4; i < 128 * 64; i += 1024)
        *(float4*)&ws[i] = *(const float4*)&W1[i];
    for (int i = t * 4; i < 64 * 128; i += 1024) {
        int n = i >> 7, k = i & 127;
        float4 v = make_float4(0.f, 0.f, 0.f, 0.f);
        if (nb + n < N_NODES) v = *(const float4*)&x[(size_t)(nb + n) * 128 + k];
        *(float4*)&xs[n * 132 + k] = v;
    }
    __syncthreads();

    const int oq = t & 15;
    const int nq = t >> 4;
    float4 acc[4];
#pragma unroll
    for (int i = 0; i < 4; ++i) acc[i] = make_float4(0.f, 0.f, 0.f, 0.f);

    for (int k = 0; k < 128; k += 4) {
        float4 wv0 = *(float4*)&ws[(k + 0) * 64 + oq * 4];
        float4 wv1 = *(float4*)&ws[(k + 1) * 64 + oq * 4];
        float4 wv2 = *(float4*)&ws[(k + 2) * 64 + oq * 4];
        float4 wv3 = *(float4*)&ws[(k + 3) * 64 + oq * 4];
#pragma unroll
        for (int i = 0; i < 4; ++i) {
            float4 xv = *(float4*)&xs[(nq * 4 + i) * 132 + k];
            acc[i].x += xv.x * wv0.x + xv.y * wv1.x + xv.z * wv2.x + xv.w * wv3.x;
            acc[i].y += xv.x * wv0.y + xv.y * wv1.y + xv.z * wv2.y + xv.w * wv3.y;
            acc[i].z += xv.x * wv0.z + xv.y * wv1.z + xv.z * wv2.z + xv.w * wv3.z;
            acc[i].w += xv.x * wv0.w + xv.y * wv1.w + xv.z * wv2.w + xv.w * wv3.w;
        }
    }
    __syncthreads();
#pragma unroll
    for (int i = 0; i < 4; ++i) {
        int n = nq * 4 + i;
        *(float4*)&xs[n * 68 + oq * 4] = acc[i];
        if (nb + n < N_NODES)
            *(float4*)&h1[(size_t)(nb + n) * 64 + oq * 4] = acc[i];
    }
    __syncthreads();
    for (int p = t; p < 512; p += 256) {
        int n = p >> 3, hd = p & 7;
        float ss = 0.f, dd = 0.f;
#pragma unroll
        for (int o = 0; o < 8; ++o) {
            float hv = xs[n * 68 + hd * 8 + o];
            ss += hv * a1s[hd * 8 + o];
            dd += hv * a1d[hd * 8 + o];
        }
        if (nb + n < N_NODES) {
            as1[(nb + n) * 8 + hd] = ss;
            ad1[(nb + n) * 8 + hd] = dd;
        }
    }
}

// ---------------------------------------------------------------------------
// K_agg1 (fused with layer-2 transform): 8-wide gathers, value-prefetch
// double-buffered one group ahead; split accumulator chains.
// ---------------------------------------------------------------------------
__global__ __launch_bounds__(256) void k_agg1f(
        const float* __restrict__ h1, const float* __restrict__ as1g,
        const float* __restrict__ ad1g, const int* __restrict__ offs,
        const int* __restrict__ csr, const float* __restrict__ b1,
        const float* __restrict__ W2, const float* __restrict__ a2s,
        const float* __restrict__ a2d,
        float* __restrict__ h2p, float* __restrict__ as2, float* __restrict__ ad2) {
    __shared__ float ws[64 * 40];            // 10 KB
    __shared__ float rows[4][64];
    const int t = threadIdx.x;
    for (int i = t; i < 64 * 40; i += 256) ws[i] = W2[i];
    __syncthreads();

    const int w = t >> 6, l = t & 63;
    const int wid = blockIdx.x * 4 + w;
    if (wid >= N_NODES) return;
    const int hd = l >> 3;
    const float ad = ad1g[wid * 8 + hd];
    const int j0 = __builtin_amdgcn_readfirstlane(offs[wid]);
    const int j1 = __builtin_amdgcn_readfirstlane(offs[wid + 1]);

    // prologue: group-0 values in flight, group-1 indices in flight
    float a[8], g[8];
    int   cn[8];
    {
        int c0[8];
#pragma unroll
        for (int i = 0; i < 8; ++i) c0[i] = csr[j0 + i];          // pad-safe
#pragma unroll
        for (int i = 0; i < 8; ++i) a[i] = as1g[(unsigned)c0[i] * 8u + (unsigned)hd];
#pragma unroll
        for (int i = 0; i < 8; ++i) g[i] = h1[(unsigned)c0[i] * 64u + (unsigned)l];
#pragma unroll
        for (int i = 0; i < 8; ++i) cn[i] = csr[j0 + 8 + i];      // pad-safe
    }

    float den0 = 0.f, den1 = 0.f, acc0 = 0.f, acc1 = 0.f;
    int j = j0;
    while (j + 8 <= j1) {                     // full groups: no predication
        float au[8], gu[8];
#pragma unroll
        for (int i = 0; i < 8; ++i) { au[i] = a[i]; gu[i] = g[i]; }
        // issue next group's value gathers (indices already resident)
#pragma unroll
        for (int i = 0; i < 8; ++i) a[i] = as1g[(unsigned)cn[i] * 8u + (unsigned)hd];
#pragma unroll
        for (int i = 0; i < 8; ++i) g[i] = h1[(unsigned)cn[i] * 64u + (unsigned)l];
        // indices two groups ahead (pad-safe: j+16+7 <= E_TOT+15)
#pragma unroll
        for (int i = 0; i < 8; ++i) cn[i] = csr[j + 16 + i];
        // compute on current group's registered values
#pragma unroll
        for (int i = 0; i < 8; ++i) {
            float e = au[i] + ad;
            e = fmaxf(e, NEG_SLOPE * e);      // leaky relu
            float xp = __expf(e);
            if (i & 1) { den1 += xp; acc1 = fmaf(xp, gu[i], acc1); }
            else       { den0 += xp; acc0 = fmaf(xp, gu[i], acc0); }
        }
        j += 8;
    }
    const int rem = j1 - j;                    // 0..7 (values already in a/g)
    if (rem) {
#pragma unroll
        for (int i = 0; i < 8; ++i) {
            float e = a[i] + ad;
            e = fmaxf(e, NEG_SLOPE * e);
            float xp = (i < rem) ? __expf(e) : 0.f;
            if (i & 1) { den1 += xp; acc1 = fmaf(xp, g[i], acc1); }
            else       { den0 += xp; acc0 = fmaf(xp, g[i], acc0); }
        }
    }

    float v = (acc0 + acc1) / (den0 + den1) + b1[l];
    v = (v > 0.f) ? v : expm1f(v);           // ELU
    rows[w][l] = v;                           // wave-private exchange

    float acc2 = 0.f;
    if (l < 40) {
#pragma unroll 8
        for (int k = 0; k < 64; ++k)
            acc2 = fmaf(rows[w][k], ws[k * 40 + l], acc2);
    }
    float ps = (l < 40) ? acc2 * a2s[l] : 0.f;
    float pd = (l < 40) ? acc2 * a2d[l] : 0.f;
#pragma unroll
    for (int off = 32; off; off >>= 1) {
        ps += __shfl_down(ps, off);
        pd += __shfl_down(pd, off);
    }
    if (l < 40) h2p[(unsigned)wid * 48u + (unsigned)l] = acc2;
    if (l == 0) { as2[wid] = ps; ad2[wid] = pd; }
}

// ---------------------------------------------------------------------------
// K_agg2: layer-2 aggregate, same pipelined structure + bias + log_softmax(40)
// ---------------------------------------------------------------------------
__global__ __launch_bounds__(256) void k_agg2(
        const float* __restrict__ h2p, const float* __restrict__ as2,
        const float* __restrict__ ad2, const int* __restrict__ offs,
        const int* __restrict__ csr, const float* __restrict__ b2,
        float* __restrict__ out) {
    int wid = (blockIdx.x * 256 + threadIdx.x) >> 6;
    int l   = threadIdx.x & 63;
    if (wid >= N_NODES) return;
    const bool act = (l < 40);
    const float ad = ad2[wid];
    const int j0 = __builtin_amdgcn_readfirstlane(offs[wid]);
    const int j1 = __builtin_amdgcn_readfirstlane(offs[wid + 1]);

    float a[8], g[8];
    int   cn[8];
    {
        int c0[8];
#pragma unroll
        for (int i = 0; i < 8; ++i) c0[i] = csr[j0 + i];
#pragma unroll
        for (int i = 0; i < 8; ++i) a[i] = as2[c0[i]];
#pragma unroll
        for (int i = 0; i < 8; ++i) g[i] = act ? h2p[(unsigned)c0[i] * 48u + (unsigned)l] : 0.f;
#pragma unroll
        for (int i = 0; i < 8; ++i) cn[i] = csr[j0 + 8 + i];
    }

    float den0 = 0.f, den1 = 0.f, acc0 = 0.f, acc1 = 0.f;
    int j = j0;
    while (j + 8 <= j1) {
        float au[8], gu[8];
#pragma unroll
        for (int i = 0; i < 8; ++i) { au[i] = a[i]; gu[i] = g[i]; }
#pragma unroll
        for (int i = 0; i < 8; ++i) a[i] = as2[cn[i]];
#pragma unroll
        for (int i = 0; i < 8; ++i) g[i] = act ? h2p[(unsigned)cn[i] * 48u + (unsigned)l] : 0.f;
#pragma unroll
        for (int i = 0; i < 8; ++i) cn[i] = csr[j + 16 + i];
#pragma unroll
        for (int i = 0; i < 8; ++i) {
            float e = au[i] + ad;
            e = fmaxf(e, NEG_SLOPE * e);
            float xp = __expf(e);
            if (i & 1) { den1 += xp; acc1 = fmaf(xp, gu[i], acc1); }
            else       { den0 += xp; acc0 = fmaf(xp, gu[i], acc0); }
        }
        j += 8;
    }
    const int rem = j1 - j;
    if (rem) {
#pragma unroll
        for (int i = 0; i < 8; ++i) {
            float e = a[i] + ad;
            e = fmaxf(e, NEG_SLOPE * e);
            float xp = (i < rem) ? __expf(e) : 0.f;
            if (i & 1) { den1 += xp; acc1 = fmaf(xp, g[i], acc1); }
            else       { den0 += xp; acc0 = fmaf(xp, g[i], acc0); }
        }
    }

    float v = act ? ((acc0 + acc1) / (den0 + den1) + b2[l]) : -1e30f;
    float m = v;
#pragma unroll
    for (int off = 32; off; off >>= 1) m = fmaxf(m, __shfl_xor(m, off));
    float ex2 = act ? __expf(v - m) : 0.f;
    float s2 = ex2;
#pragma unroll
    for (int off = 32; off; off >>= 1) s2 += __shfl_xor(s2, off);
    if (act) out[(size_t)wid * 40 + l] = v - m - __logf(s2);
}

// ---------------------------------------------------------------------------
extern "C" void kernel_launch(void* const* d_in, const int* in_sizes, int n_in,
                              void* d_out, int out_size, void* d_ws, size_t ws_size,
                              hipStream_t stream) {
    const float* x   = (const float*)d_in[0];
    const void*  ei  = d_in[1];
    const float* W1  = (const float*)d_in[2];
    const float* a1s = (const float*)d_in[3];
    const float* a1d = (const float*)d_in[4];
    const float* b1  = (const float*)d_in[5];
    const float* W2  = (const float*)d_in[6];
    const float* a2s = (const float*)d_in[7];
    const float* a2d = (const float*)d_in[8];
    const float* b2  = (const float*)d_in[9];
    float* out = (float*)d_out;

    // workspace layout (floats)
    float* fws = (float*)d_ws;
    float* h1  = fws + 0;                     // 3,200,000
    float* as1 = fws + 3200000;               //   400,000
    float* ad1 = fws + 3600000;               //   400,000
    float* h2p = fws + 4000000;               // 2,400,000 (stride 48)
    float* as2 = fws + 6400000;               //    50,000
    float* ad2 = fws + 6450000;               //    50,000
    int*   offs     = (int*)(fws + 6500000);  // 50,001
    int*   cursor   = offs + (N_NODES + 1);   // 50,000
    int*   csr      = cursor + N_NODES;       // 850,000 + 16 pad
    int*   partials = csr + E_TOT + 16;       // 49
    int*   flag     = partials + SCAN_BLOCKS; // 1

    k_detect0<<<64, 256, 0, stream>>>((const unsigned int*)ei, flag, offs);

    int egrid = (E_TOT + 255) / 256;
    k_count<<<egrid, 256, 0, stream>>>(ei, flag, offs);
    k_scanA<<<SCAN_BLOCKS, 1024, 0, stream>>>(offs, partials);
    k_scanC<<<SCAN_BLOCKS, 1024, 0, stream>>>(offs, partials, cursor);
    k_fill<<<egrid, 256, 0, stream>>>(ei, flag, cursor, csr);

    k1_transform<<<(N_NODES + 63) / 64, 256, 0, stream>>>(x, W1, a1s, a1d, h1, as1, ad1);

    int ngrid = (N_NODES + 3) / 4;
    k_agg1f<<<ngrid, 256, 0, stream>>>(h1, as1, ad1, offs, csr, b1,
                                       W2, a2s, a2d, h2p, as2, ad2);
    k_agg2<<<ngrid, 256, 0, stream>>>(h2p, as2, ad2, offs, csr, b2, out);
}

// Round 8
// 295.802 us; speedup vs baseline: 1.0203x; 1.0203x over previous
//
#include <hip/hip_runtime.h>
#include <hip/hip_bf16.h>
#include <math.h>

#define N_NODES 50000
#define E_EDGES 800000
#define E_TOT   850000   // + self loops
#define NEG_SLOPE 0.2f
#define SCAN_BLOCKS 49   // ceil(50001/1024)
#define BUCKETS 512
#define RNG 98           // dst nodes per bucket (512*98 = 50176 >= 50000)
#define FA_CHUNK 16384   // edges per fillA workgroup
#define FA_THREADS 512
#define FA_EPT (FA_CHUNK / FA_THREADS)   // 32 edges/thread

// ---------------------------------------------------------------------------
// Fused: zero offs histogram + int64/int32 edge-index detection
// ---------------------------------------------------------------------------
__global__ __launch_bounds__(256) void k_detect0(const unsigned int* __restrict__ ei,
                                                 int* __restrict__ flag,
                                                 int* __restrict__ offs) {
    int gid = blockIdx.x * 256 + threadIdx.x;
    for (int i = gid; i <= N_NODES; i += gridDim.x * 256) offs[i] = 0;
    if (blockIdx.x == 0) {
        __shared__ int anynz;
        if (threadIdx.x == 0) anynz = 0;
        __syncthreads();
        int nz = 0;
        for (int i = threadIdx.x; i < 2048; i += 256)
            nz |= (ei[2 * i + 1] != 0u);
        if (nz) atomicOr(&anynz, 1);
        __syncthreads();
        if (threadIdx.x == 0) *flag = (anynz == 0) ? 1 : 0;
    }
}

__device__ __forceinline__ void edge_nodes(const void* ei, int is64, int e, int& s, int& d) {
    if (e >= E_EDGES) { s = d = e - E_EDGES; return; }   // self loop
    if (is64) {
        const long long* p = (const long long*)ei;
        s = (int)p[e]; d = (int)p[E_EDGES + e];
    } else {
        const int* p = (const int*)ei;
        s = p[e]; d = p[E_EDGES + e];
    }
}

// ---------------------------------------------------------------------------
// CSR build: histogram -> parallel scan -> bucketed two-phase fill
// ---------------------------------------------------------------------------
__global__ void k_count(const void* __restrict__ ei, const int* __restrict__ flag,
                        int* __restrict__ counts) {
    int e = blockIdx.x * 256 + threadIdx.x;
    if (e >= E_TOT) return;
    int s, d;
    edge_nodes(ei, *flag, e, s, d);
    atomicAdd(&counts[d], 1);
}

// block-local exclusive scan (in place) + per-block total
__global__ __launch_bounds__(1024) void k_scanA(int* __restrict__ offs,
                                                int* __restrict__ partials) {
    __shared__ int lds[1024];
    const int t   = threadIdx.x;
    const int idx = blockIdx.x * 1024 + t;
    int v = (idx <= N_NODES) ? offs[idx] : 0;
    lds[t] = v;
    __syncthreads();
    for (int off = 1; off < 1024; off <<= 1) {
        int u = (t >= off) ? lds[t - off] : 0;
        __syncthreads();
        lds[t] += u;
        __syncthreads();
    }
    int incl = lds[t];
    if (idx <= N_NODES) offs[idx] = incl - v;         // exclusive within chunk
    if (t == 1023) partials[blockIdx.x] = incl;       // chunk total
}

// add scanned partials prefix; emit final offs + cursor copy + bucket cursors
__global__ __launch_bounds__(1024) void k_scanC(int* __restrict__ offs,
                                                const int* __restrict__ partials,
                                                int* __restrict__ cursor,
                                                int* __restrict__ bcur) {
    __shared__ int sprefix;
    const int t   = threadIdx.x;
    const int bid = blockIdx.x;
    if (t < 64) {
        int p = (t < bid) ? partials[t] : 0;          // bid <= 48 < 64
#pragma unroll
        for (int off = 32; off; off >>= 1) p += __shfl_down(p, off);
        if (t == 0) sprefix = p;
    }
    __syncthreads();
    const int idx = bid * 1024 + t;
    if (idx <= N_NODES) {
        int v = offs[idx] + sprefix;
        offs[idx] = v;
        if (idx < N_NODES) cursor[idx] = v;
        if ((idx % RNG) == 0 && idx < N_NODES) bcur[idx / RNG] = v;   // b = 0..510
        if (idx == N_NODES) bcur[BUCKETS - 1] = v;                    // unused, safe init
    }
}

// phase A: LDS-binned staging. Each wg: 16K edges -> 512 bucket runs.
__global__ __launch_bounds__(FA_THREADS) void k_fillA(const void* __restrict__ ei,
                                                      const int* __restrict__ flag,
                                                      int* __restrict__ bcur,
                                                      unsigned int* __restrict__ stage) {
    __shared__ int cnt[BUCKETS];
    __shared__ int base[BUCKETS];
    __shared__ int lofs[BUCKETS];
    const int t  = threadIdx.x;
    const int cb = blockIdx.x * FA_CHUNK;
    const int is64 = *flag;
    cnt[t] = 0;
    __syncthreads();
    unsigned int pk[FA_EPT];
#pragma unroll
    for (int i = 0; i < FA_EPT; ++i) {
        int e = cb + i * FA_THREADS + t;
        pk[i] = 0xFFFFFFFFu;
        if (e < E_TOT) {
            int s, d;
            edge_nodes(ei, is64, e, s, d);
            pk[i] = ((unsigned)d << 16) | (unsigned)s;
            atomicAdd(&cnt[(unsigned)d / RNG], 1);
        }
    }
    __syncthreads();
    {
        int c = cnt[t];
        base[t] = c ? atomicAdd(&bcur[t], c) : 0;
        lofs[t] = 0;
    }
    __syncthreads();
#pragma unroll
    for (int i = 0; i < FA_EPT; ++i) {
        if (pk[i] != 0xFFFFFFFFu) {
            int b  = (pk[i] >> 16) / RNG;
            int lp = atomicAdd(&lofs[b], 1);
            stage[base[b] + lp] = pk[i];
        }
    }
}

// phase B: per-bucket reorder into exact dst-grouped csr (wg-local window).
__global__ __launch_bounds__(256) void k_fillB(const unsigned int* __restrict__ stage,
                                               const int* __restrict__ offs,
                                               int* __restrict__ cursor,
                                               int* __restrict__ csr) {
    const int b = blockIdx.x;
    const int t = threadIdx.x;
    if (b == 0 && t < 16) csr[E_TOT + t] = 0;          // pad (valid node id 0)
    const int lo  = b * RNG;
    const int hi  = min(lo + RNG, N_NODES);
    const int rb0 = offs[lo];
    const int rb1 = offs[hi];
    for (int i = rb0 + t; i < rb1; i += 256) {
        unsigned int v = stage[i];
        int d   = (int)(v >> 16);
        int pos = atomicAdd(&cursor[d], 1);
        csr[pos] = (int)(v & 0xFFFFu);
    }
}

// ---------------------------------------------------------------------------
// K1: h1 = x @ W1 (50000x128 @ 128x64) + per-node attention halves
// ---------------------------------------------------------------------------
__global__ __launch_bounds__(256) void k1_transform(
        const float* __restrict__ x, const float* __restrict__ W1,
        const float* __restrict__ a1s, const float* __restrict__ a1d,
        float* __restrict__ h1, float* __restrict__ as1, float* __restrict__ ad1) {
    __shared__ float ws[128 * 64];
    __shared__ float xs[64 * 132];
    const int t  = threadIdx.x;
    const int nb = blockIdx.x * 64;
    for (int i = t * 4; i < 128 * 64; i += 1024)
        *(float4*)&ws[i] = *(const float4*)&W1[i];
    for (int i = t * 4; i < 64 * 128; i += 1024) {
        int n = i >> 7, k = i & 127;
        float4 v = make_float4(0.f, 0.f, 0.f, 0.f);
        if (nb + n < N_NODES) v = *(const float4*)&x[(size_t)(nb + n) * 128 + k];
        *(float4*)&xs[n * 132 + k] = v;
    }
    __syncthreads();

    const int oq = t & 15;
    const int nq = t >> 4;
    float4 acc[4];
#pragma unroll
    for (int i = 0; i < 4; ++i) acc[i] = make_float4(0.f, 0.f, 0.f, 0.f);

    for (int k = 0; k < 128; k += 4) {
        float4 wv0 = *(float4*)&ws[(k + 0) * 64 + oq * 4];
        float4 wv1 = *(float4*)&ws[(k + 1) * 64 + oq * 4];
        float4 wv2 = *(float4*)&ws[(k + 2) * 64 + oq * 4];
        float4 wv3 = *(float4*)&ws[(k + 3) * 64 + oq * 4];
#pragma unroll
        for (int i = 0; i < 4; ++i) {
            float4 xv = *(float4*)&xs[(nq * 4 + i) * 132 + k];
            acc[i].x += xv.x * wv0.x + xv.y * wv1.x + xv.z * wv2.x + xv.w * wv3.x;
            acc[i].y += xv.x * wv0.y + xv.y * wv1.y + xv.z * wv2.y + xv.w * wv3.y;
            acc[i].z += xv.x * wv0.z + xv.y * wv1.z + xv.z * wv2.z + xv.w * wv3.z;
            acc[i].w += xv.x * wv0.w + xv.y * wv1.w + xv.z * wv2.w + xv.w * wv3.w;
        }
    }
    __syncthreads();
#pragma unroll
    for (int i = 0; i < 4; ++i) {
        int n = nq * 4 + i;
        *(float4*)&xs[n * 68 + oq * 4] = acc[i];
        if (nb + n < N_NODES)
            *(float4*)&h1[(size_t)(nb + n) * 64 + oq * 4] = acc[i];
    }
    __syncthreads();
    for (int p = t; p < 512; p += 256) {
        int n = p >> 3, hd = p & 7;
        float ss = 0.f, dd = 0.f;
#pragma unroll
        for (int o = 0; o < 8; ++o) {
            float hv = xs[n * 68 + hd * 8 + o];
            ss += hv * a1s[hd * 8 + o];
            dd += hv * a1d[hd * 8 + o];
        }
        if (nb + n < N_NODES) {
            as1[(nb + n) * 8 + hd] = ss;
            ad1[(nb + n) * 8 + hd] = dd;
        }
    }
}

// ---------------------------------------------------------------------------
// K_agg1 (fused with layer-2 transform): 8-wide gathers, value-prefetch
// double-buffered one group ahead; split accumulator chains.
// ---------------------------------------------------------------------------
__global__ __launch_bounds__(256) void k_agg1f(
        const float* __restrict__ h1, const float* __restrict__ as1g,
        const float* __restrict__ ad1g, const int* __restrict__ offs,
        const int* __restrict__ csr, const float* __restrict__ b1,
        const float* __restrict__ W2, const float* __restrict__ a2s,
        const float* __restrict__ a2d,
        float* __restrict__ h2p, float* __restrict__ as2, float* __restrict__ ad2) {
    __shared__ float ws[64 * 40];            // 10 KB
    __shared__ float rows[4][64];
    const int t = threadIdx.x;
    for (int i = t; i < 64 * 40; i += 256) ws[i] = W2[i];
    __syncthreads();

    const int w = t >> 6, l = t & 63;
    const int wid = blockIdx.x * 4 + w;
    if (wid >= N_NODES) return;
    const int hd = l >> 3;
    const float ad = ad1g[wid * 8 + hd];
    const int j0 = __builtin_amdgcn_readfirstlane(offs[wid]);
    const int j1 = __builtin_amdgcn_readfirstlane(offs[wid + 1]);

    // prologue: group-0 values in flight, group-1 indices in flight
    float a[8], g[8];
    int   cn[8];
    {
        int c0[8];
#pragma unroll
        for (int i = 0; i < 8; ++i) c0[i] = csr[j0 + i];          // pad-safe
#pragma unroll
        for (int i = 0; i < 8; ++i) a[i] = as1g[(unsigned)c0[i] * 8u + (unsigned)hd];
#pragma unroll
        for (int i = 0; i < 8; ++i) g[i] = h1[(unsigned)c0[i] * 64u + (unsigned)l];
#pragma unroll
        for (int i = 0; i < 8; ++i) cn[i] = csr[j0 + 8 + i];      // pad-safe
    }

    float den0 = 0.f, den1 = 0.f, acc0 = 0.f, acc1 = 0.f;
    int j = j0;
    while (j + 8 <= j1) {                     // full groups: no predication
        float au[8], gu[8];
#pragma unroll
        for (int i = 0; i < 8; ++i) { au[i] = a[i]; gu[i] = g[i]; }
        // issue next group's value gathers (indices already resident)
#pragma unroll
        for (int i = 0; i < 8; ++i) a[i] = as1g[(unsigned)cn[i] * 8u + (unsigned)hd];
#pragma unroll
        for (int i = 0; i < 8; ++i) g[i] = h1[(unsigned)cn[i] * 64u + (unsigned)l];
        // indices two groups ahead (pad-safe)
#pragma unroll
        for (int i = 0; i < 8; ++i) cn[i] = csr[j + 16 + i];
        // compute on current group's registered values
#pragma unroll
        for (int i = 0; i < 8; ++i) {
            float e = au[i] + ad;
            e = fmaxf(e, NEG_SLOPE * e);      // leaky relu
            float xp = __expf(e);
            if (i & 1) { den1 += xp; acc1 = fmaf(xp, gu[i], acc1); }
            else       { den0 += xp; acc0 = fmaf(xp, gu[i], acc0); }
        }
        j += 8;
    }
    const int rem = j1 - j;                    // 0..7 (values already in a/g)
    if (rem) {
#pragma unroll
        for (int i = 0; i < 8; ++i) {
            float e = a[i] + ad;
            e = fmaxf(e, NEG_SLOPE * e);
            float xp = (i < rem) ? __expf(e) : 0.f;
            if (i & 1) { den1 += xp; acc1 = fmaf(xp, g[i], acc1); }
            else       { den0 += xp; acc0 = fmaf(xp, g[i], acc0); }
        }
    }

    float v = (acc0 + acc1) / (den0 + den1) + b1[l];
    v = (v > 0.f) ? v : expm1f(v);           // ELU
    rows[w][l] = v;                           // wave-private exchange

    float acc2 = 0.f;
    if (l < 40) {
#pragma unroll 8
        for (int k = 0; k < 64; ++k)
            acc2 = fmaf(rows[w][k], ws[k * 40 + l], acc2);
    }
    float ps = (l < 40) ? acc2 * a2s[l] : 0.f;
    float pd = (l < 40) ? acc2 * a2d[l] : 0.f;
#pragma unroll
    for (int off = 32; off; off >>= 1) {
        ps += __shfl_down(ps, off);
        pd += __shfl_down(pd, off);
    }
    if (l < 40) h2p[(unsigned)wid * 48u + (unsigned)l] = acc2;
    if (l == 0) { as2[wid] = ps; ad2[wid] = pd; }
}

// ---------------------------------------------------------------------------
// K_agg2: layer-2 aggregate, same pipelined structure + bias + log_softmax(40)
// ---------------------------------------------------------------------------
__global__ __launch_bounds__(256) void k_agg2(
        const float* __restrict__ h2p, const float* __restrict__ as2,
        const float* __restrict__ ad2, const int* __restrict__ offs,
        const int* __restrict__ csr, const float* __restrict__ b2,
        float* __restrict__ out) {
    int wid = (blockIdx.x * 256 + threadIdx.x) >> 6;
    int l   = threadIdx.x & 63;
    if (wid >= N_NODES) return;
    const bool act = (l < 40);
    const float ad = ad2[wid];
    const int j0 = __builtin_amdgcn_readfirstlane(offs[wid]);
    const int j1 = __builtin_amdgcn_readfirstlane(offs[wid + 1]);

    float a[8], g[8];
    int   cn[8];
    {
        int c0[8];
#pragma unroll
        for (int i = 0; i < 8; ++i) c0[i] = csr[j0 + i];
#pragma unroll
        for (int i = 0; i < 8; ++i) a[i] = as2[c0[i]];
#pragma unroll
        for (int i = 0; i < 8; ++i) g[i] = act ? h2p[(unsigned)c0[i] * 48u + (unsigned)l] : 0.f;
#pragma unroll
        for (int i = 0; i < 8; ++i) cn[i] = csr[j0 + 8 + i];
    }

    float den0 = 0.f, den1 = 0.f, acc0 = 0.f, acc1 = 0.f;
    int j = j0;
    while (j + 8 <= j1) {
        float au[8], gu[8];
#pragma unroll
        for (int i = 0; i < 8; ++i) { au[i] = a[i]; gu[i] = g[i]; }
#pragma unroll
        for (int i = 0; i < 8; ++i) a[i] = as2[cn[i]];
#pragma unroll
        for (int i = 0; i < 8; ++i) g[i] = act ? h2p[(unsigned)cn[i] * 48u + (unsigned)l] : 0.f;
#pragma unroll
        for (int i = 0; i < 8; ++i) cn[i] = csr[j + 16 + i];
#pragma unroll
        for (int i = 0; i < 8; ++i) {
            float e = au[i] + ad;
            e = fmaxf(e, NEG_SLOPE * e);
            float xp = __expf(e);
            if (i & 1) { den1 += xp; acc1 = fmaf(xp, gu[i], acc1); }
            else       { den0 += xp; acc0 = fmaf(xp, gu[i], acc0); }
        }
        j += 8;
    }
    const int rem = j1 - j;
    if (rem) {
#pragma unroll
        for (int i = 0; i < 8; ++i) {
            float e = a[i] + ad;
            e = fmaxf(e, NEG_SLOPE * e);
            float xp = (i < rem) ? __expf(e) : 0.f;
            if (i & 1) { den1 += xp; acc1 = fmaf(xp, g[i], acc1); }
            else       { den0 += xp; acc0 = fmaf(xp, g[i], acc0); }
        }
    }

    float v = act ? ((acc0 + acc1) / (den0 + den1) + b2[l]) : -1e30f;
    float m = v;
#pragma unroll
    for (int off = 32; off; off >>= 1) m = fmaxf(m, __shfl_xor(m, off));
    float ex2 = act ? __expf(v - m) : 0.f;
    float s2 = ex2;
#pragma unroll
    for (int off = 32; off; off >>= 1) s2 += __shfl_xor(s2, off);
    if (act) out[(size_t)wid * 40 + l] = v - m - __logf(s2);
}

// ---------------------------------------------------------------------------
extern "C" void kernel_launch(void* const* d_in, const int* in_sizes, int n_in,
                              void* d_out, int out_size, void* d_ws, size_t ws_size,
                              hipStream_t stream) {
    const float* x   = (const float*)d_in[0];
    const void*  ei  = d_in[1];
    const float* W1  = (const float*)d_in[2];
    const float* a1s = (const float*)d_in[3];
    const float* a1d = (const float*)d_in[4];
    const float* b1  = (const float*)d_in[5];
    const float* W2  = (const float*)d_in[6];
    const float* a2s = (const float*)d_in[7];
    const float* a2d = (const float*)d_in[8];
    const float* b2  = (const float*)d_in[9];
    float* out = (float*)d_out;

    // workspace layout (floats)
    float* fws = (float*)d_ws;
    float* h1  = fws + 0;                     // 3,200,000
    float* as1 = fws + 3200000;               //   400,000
    float* ad1 = fws + 3600000;               //   400,000
    float* h2p = fws + 4000000;               // 2,400,000 (stride 48)
    float* as2 = fws + 6400000;               //    50,000
    float* ad2 = fws + 6450000;               //    50,000
    int*   offs     = (int*)(fws + 6500000);  // 50,001
    int*   cursor   = offs + (N_NODES + 1);   // 50,000
    int*   csr      = cursor + N_NODES;       // 850,000 + 16 pad
    int*   partials = csr + E_TOT + 16;       // 49
    int*   flag     = partials + SCAN_BLOCKS; // 1
    int*   bcur     = flag + 1;               // 512
    unsigned int* stage = (unsigned int*)(bcur + BUCKETS);  // 850,000

    k_detect0<<<64, 256, 0, stream>>>((const unsigned int*)ei, flag, offs);

    int egrid = (E_TOT + 255) / 256;
    k_count<<<egrid, 256, 0, stream>>>(ei, flag, offs);
    k_scanA<<<SCAN_BLOCKS, 1024, 0, stream>>>(offs, partials);
    k_scanC<<<SCAN_BLOCKS, 1024, 0, stream>>>(offs, partials, cursor, bcur);

    int fagrid = (E_TOT + FA_CHUNK - 1) / FA_CHUNK;   // 52
    k_fillA<<<fagrid, FA_THREADS, 0, stream>>>(ei, flag, bcur, stage);
    k_fillB<<<BUCKETS - 1, 256, 0, stream>>>(stage, offs, cursor, csr);

    k1_transform<<<(N_NODES + 63) / 64, 256, 0, stream>>>(x, W1, a1s, a1d, h1, as1, ad1);

    int ngrid = (N_NODES + 3) / 4;
    k_agg1f<<<ngrid, 256, 0, stream>>>(h1, as1, ad1, offs, csr, b1,
                                       W2, a2s, a2d, h2p, as2, ad2);
    k_agg2<<<ngrid, 256, 0, stream>>>(h2p, as2, ad2, offs, csr, b2, out);
}